// Round 9
// baseline (136.068 us; speedup 1.0000x reference)
//
#include <hip/hip_runtime.h>

// StrokeField R15: vectorized id stream (uint4 = 8 strokes per VMEM) +
// next-block prefetch in kM's blend walk.
// R14 post-mortem: sort deletion 240->130us. kM 61us, VALUBusy 67%,
// FETCH 13.5MB / WRITE 57MB (logical outputs only -- not memory bound).
// Remaining bubble: ONE dependent per-lane u16 VMEM gather per stroke
// (L2 ~200cy) -- each 4-stroke group stalled on a fresh VMEM round trip.
// R15: cell rows are 1024B-aligned, so an aligned uint4 load gives 8 ids
// in one VMEM op; all 16 LDS gathers for the block issue together
// (~224 issue-cy > LDS latency), and the next uint4 is prefetched before
// blending the current block. Scalar top-tail until remaining%8==0.
// Math/order/early-exit bit-identical to R14.

#define NC_DIM 16
#define NC (NC_DIM * NC_DIM * NC_DIM)
#define MAXS 512
#define CELL_INV 8.0f

typedef unsigned short u16;
typedef unsigned long long u64;

__device__ __forceinline__ void contract_pt(float x, float y, float z,
                                            float& cx, float& cy, float& cz) {
    float n2 = fmaf(x, x, fmaf(y, y, z * z));
    float nn = fmaxf(__builtin_amdgcn_sqrtf(n2), 1e-9f);
    float invn = 1.0f / nn;
    float scl = (nn <= 1.0f) ? 0.5f : (2.0f - invn) * (0.5f * invn);
    cx = x * scl; cy = y * scl; cz = z * scl;
}

__device__ __forceinline__ int cid_of(float cx, float cy, float cz) {
    int ix = (int)floorf((cx + 1.0f) * CELL_INV);
    int iy = (int)floorf((cy + 1.0f) * CELL_INV);
    int iz = (int)floorf((cz + 1.0f) * CELL_INV);
    ix = min(max(ix, 0), 15); iy = min(max(iy, 0), 15); iz = min(max(iz, 0), 15);
    return ix | (iy << 4) | (iz << 8);
}

// KE: per-cell ordered stroke sublist (AABB vs sphere, exact-zero margin).
// One wave per cell; ballot-compacted ascending ids. (Verified R6/R7/R14.)
__global__ __launch_bounds__(256) void kE(
    const float* __restrict__ shape, u16* __restrict__ cellList,
    int* __restrict__ strokeCnt, int ns)
{
    int wave = (blockIdx.x * blockDim.x + threadIdx.x) >> 6;
    int lane = threadIdx.x & 63;
    if (wave >= NC) return;
    int ix = wave & 15, iy = (wave >> 4) & 15, iz = wave >> 8;
    float lox = -1.0f + ix * 0.125f, hix = lox + 0.125f;
    float loy = -1.0f + iy * 0.125f, hiy = loy + 0.125f;
    float loz = -1.0f + iz * 0.125f, hiz = loz + 0.125f;
    int cnt = 0;
    u16* lst = cellList + (size_t)wave * MAXS;
    for (int base = 0; base < ns; base += 64) {
        int s = base + lane;
        bool pass = false;
        if (s < ns) {
            float4 sp = ((const float4*)shape)[s];
            float dx = sp.x - fminf(fmaxf(sp.x, lox), hix);
            float dy = sp.y - fminf(fmaxf(sp.y, loy), hiy);
            float dz = sp.z - fminf(fmaxf(sp.z, loz), hiz);
            float d2 = fmaf(dx, dx, fmaf(dy, dy, dz * dz));
            float rr = sp.w + 0.101f;
            pass = d2 <= rr * rr;
        }
        u64 m = __ballot(pass);
        if (pass) lst[cnt + __popcll(m & ((1ull << lane) - 1ull))] = (u16)s;
        cnt += __popcll(m);
    }
    if (lane == 0) strokeCnt[wave] = cnt;
}

// KM: fused contract + per-lane cell-list blend + coalesced outputs.
// One point per thread, original order. 8-stroke blocks: ids from one
// aligned uint4 (prefetched one block ahead); 16 LDS gathers issue
// together; T==0 per-block break (exact).
__global__ __launch_bounds__(256) void kM(
    const float* __restrict__ coords, const float* __restrict__ shape,
    const float* __restrict__ color, const float* __restrict__ alpha,
    const u16* __restrict__ cellList, const int* __restrict__ strokeCnt,
    float* __restrict__ out, int n, int ns)
{
    __shared__ float4 sA[MAXS];   // (ax, ay, az, K = 0.5 - 5r)
    __shared__ float4 sB[MAXS];   // (dp, cr, cg, cb)
    for (int s = threadIdx.x; s < ns; s += 256) {
        float4 sp = ((const float4*)shape)[s];
        sA[s] = make_float4(sp.x, sp.y, sp.z, fmaf(-5.0f, sp.w, 0.5f));
        sB[s] = make_float4(fmaxf(alpha[s], 0.0f) * 50.0f,
                            color[3 * s], color[3 * s + 1], color[3 * s + 2]);
    }
    __syncthreads();

    int i = blockIdx.x * 256 + threadIdx.x;
    if (i >= n) return;

    float cx, cy, cz;
    contract_pt(coords[3 * i], coords[3 * i + 1], coords[3 * i + 2], cx, cy, cz);
    float* cw = out + 4 * (size_t)n;
    cw[3 * i] = cx; cw[3 * i + 1] = cy; cw[3 * i + 2] = cz;

    int cid = cid_of(cx, cy, cz);
    int nl = strokeCnt[cid];
    const u16* lst = cellList + (size_t)cid * MAXS;

    float T = 1.0f, Ad = 0.0f, Ar = 0.0f, Ag = 0.0f, Ab = 0.0f;

#define BLEND1(AV, BV) { \
    float dx = cx - AV.x, dy = cy - AV.y, dz = cz - AV.z; \
    float d2 = fmaf(dx, dx, fmaf(dy, dy, dz * dz)); \
    float omt = __builtin_amdgcn_fmed3f( \
        fmaf(5.0f, __builtin_amdgcn_sqrtf(d2), AV.w), 0.0f, 1.0f); \
    float Tn = omt * T; float tT = T - Tn; \
    Ad = fmaf(tT, BV.x, Ad); Ar = fmaf(tT, BV.y, Ar); \
    Ag = fmaf(tT, BV.z, Ag); Ab = fmaf(tT, BV.w, Ab); T = Tn; }

    int j = nl - 1;                          // descending = composite order
    // Scalar top-tail until remaining count (j+1) is a multiple of 8.
    while (j >= 0 && ((j + 1) & 7)) {
        int id = lst[j];
        float4 a = sA[id], b = sB[id];
        BLEND1(a, b);
        --j;
        if (T == 0.0f) j = -1;
    }
    // Full 8-stroke blocks; one aligned uint4 id load per block, prefetched.
    if (j >= 7) {
        const uint4* lp = (const uint4*)lst;     // row base is 1024B-aligned
        int blk = (j - 7) >> 3;                  // elements [8blk .. 8blk+7]
        uint4 v = lp[blk];
        for (;;) {
            uint4 vn;
            if (blk > 0) vn = lp[blk - 1];       // prefetch next (lower) block
            int t7 = (int)(v.w >> 16), t6 = (int)(v.w & 0xFFFF);
            int t5 = (int)(v.z >> 16), t4 = (int)(v.z & 0xFFFF);
            int t3 = (int)(v.y >> 16), t2 = (int)(v.y & 0xFFFF);
            int t1 = (int)(v.x >> 16), t0 = (int)(v.x & 0xFFFF);
            {
                float4 a7 = sA[t7], b7 = sB[t7];
                float4 a6 = sA[t6], b6 = sB[t6];
                float4 a5 = sA[t5], b5 = sB[t5];
                float4 a4 = sA[t4], b4 = sB[t4];
                BLEND1(a7, b7); BLEND1(a6, b6);
                BLEND1(a5, b5); BLEND1(a4, b4);
            }
            {
                float4 a3 = sA[t3], b3 = sB[t3];
                float4 a2 = sA[t2], b2 = sB[t2];
                float4 a1 = sA[t1], b1 = sB[t1];
                float4 a0 = sA[t0], b0 = sB[t0];
                BLEND1(a3, b3); BLEND1(a2, b2);
                BLEND1(a1, b1); BLEND1(a0, b0);
            }
            if (T == 0.0f || blk == 0) break;
            v = vn; --blk;
        }
    }
#undef BLEND1

    float inv = 1.0f / (1.0f + 1e-6f - T);
    out[i] = Ad;
    float* rgb = out + n;
    rgb[3 * i]     = fminf(fmaxf(Ar * inv, 0.0f), 1.0f);
    rgb[3 * i + 1] = fminf(fmaxf(Ag * inv, 0.0f), 1.0f);
    rgb[3 * i + 2] = fminf(fmaxf(Ab * inv, 0.0f), 1.0f);
}

// ---- Fallback: R4 direct kernel ----
#define PTS 4
__global__ __launch_bounds__(256) void stroke_direct(
    const float* __restrict__ coords, const float* __restrict__ shape,
    const float* __restrict__ color, const float* __restrict__ alpha,
    float* __restrict__ out, int n, int ns)
{
    __shared__ float4 fA[MAXS + 1];
    __shared__ float4 fB[MAXS + 1];
    for (int s = threadIdx.x; s < ns; s += blockDim.x) {
        float4 sp = ((const float4*)shape)[s];
        fA[s + 1] = make_float4(sp.x, sp.y, sp.z, fmaf(-5.0f, sp.w, 0.5f));
        fB[s + 1] = make_float4(fmaxf(alpha[s], 0.0f) * 50.0f,
                                color[3 * s], color[3 * s + 1], color[3 * s + 2]);
    }
    __syncthreads();
    const int base = blockIdx.x * (blockDim.x * PTS) + threadIdx.x;
    float cx[PTS], cy[PTS], cz[PTS], T[PTS], Ad[PTS], Ar[PTS], Ag[PTS], Ab[PTS];
#pragma unroll
    for (int k = 0; k < PTS; ++k) {
        int i = base + k * 256; i = (i < n) ? i : (n - 1);
        contract_pt(coords[3 * i], coords[3 * i + 1], coords[3 * i + 2],
                    cx[k], cy[k], cz[k]);
        T[k] = 1.0f; Ad[k] = Ar[k] = Ag[k] = Ab[k] = 0.0f;
    }
    float4 a = fA[ns], b = fB[ns];
#pragma unroll 2
    for (int s = ns - 1; s >= 0; --s) {
        float4 an = fA[s], bn = fB[s];
#pragma unroll
        for (int k = 0; k < PTS; ++k) {
            float dx = cx[k] - a.x, dy = cy[k] - a.y, dz = cz[k] - a.z;
            float d2 = fmaf(dx, dx, fmaf(dy, dy, dz * dz));
            float dist = __builtin_amdgcn_sqrtf(d2);
            float omt = fminf(fmaxf(fmaf(5.0f, dist, a.w), 0.0f), 1.0f);
            float Tn = omt * T[k];
            float tT = T[k] - Tn;
            Ad[k] = fmaf(tT, b.x, Ad[k]); Ar[k] = fmaf(tT, b.y, Ar[k]);
            Ag[k] = fmaf(tT, b.z, Ag[k]); Ab[k] = fmaf(tT, b.w, Ab[k]);
            T[k] = Tn;
        }
        a = an; b = bn;
    }
    float* rgb = out + n;
    float* cw  = out + 4 * (size_t)n;
#pragma unroll
    for (int k = 0; k < PTS; ++k) {
        int i = base + k * 256;
        if (i >= n) break;
        float inv = 1.0f / (1.0f + 1e-6f - T[k]);
        out[i] = Ad[k];
        rgb[3 * i]     = fminf(fmaxf(Ar[k] * inv, 0.0f), 1.0f);
        rgb[3 * i + 1] = fminf(fmaxf(Ag[k] * inv, 0.0f), 1.0f);
        rgb[3 * i + 2] = fminf(fmaxf(Ab[k] * inv, 0.0f), 1.0f);
        cw[3 * i]     = cx[k];
        cw[3 * i + 1] = cy[k];
        cw[3 * i + 2] = cz[k];
    }
}

extern "C" void kernel_launch(void* const* d_in, const int* in_sizes, int n_in,
                              void* d_out, int out_size, void* d_ws, size_t ws_size,
                              hipStream_t stream) {
    const float* coords = (const float*)d_in[0];
    const float* shape  = (const float*)d_in[1];
    const float* color  = (const float*)d_in[2];
    const float* alpha  = (const float*)d_in[3];
    float* out = (float*)d_out;

    int n  = in_sizes[0] / 3;
    int ns = in_sizes[1] / 4;

    size_t o_list = 0;                                   // NC*MAXS*2 = 4MB
    size_t o_cnt  = (size_t)NC * MAXS * 2;               // NC*4
    size_t need   = o_cnt + (size_t)NC * 4;

    if (ws_size >= need && ns <= MAXS && n >= 1) {
        char* w = (char*)d_ws;
        u16* cellList  = (u16*)(w + o_list);
        int* strokeCnt = (int*)(w + o_cnt);

        kE<<<(NC * 64) / 256, 256, 0, stream>>>(shape, cellList, strokeCnt, ns);
        kM<<<(n + 255) / 256, 256, 0, stream>>>(coords, shape, color, alpha,
                                                cellList, strokeCnt, out, n, ns);
    } else {
        int per_block = 256 * PTS;
        int grid = (n + per_block - 1) / per_block;
        stroke_direct<<<grid, 256, 0, stream>>>(coords, shape, color, alpha, out, n, ns);
    }
}